// Round 1
// baseline (80.605 us; speedup 1.0000x reference)
//
#include <hip/hip_runtime.h>
#include <math.h>

// Problem constants (setup_inputs): data1/data2 = (2, 4, 4096, 3) fp32, dim = 0.
constexpr int kB   = 2;
constexpr int kT   = 4;
constexpr int kBT  = kB * kT;       // 8 (b,t) slices
constexpr int kN   = 4096;          // points per slice (both sets)
constexpr int kR   = 4;             // set1 points per thread (register-tiled)
constexpr int kBLK = 256;           // threads per block
constexpr int kSP1 = kR * kBLK;     // 1024 set1 points per block
constexpr int kS1C = kN / kSP1;     // 4 set1 chunks
constexpr int kSP2 = 64;            // data2 points per block (chunk) -- was 128
constexpr int kS2C = kN / kSP2;     // 64 data2 chunks
constexpr int kNG  = kSP2 / 4;      // 16 groups of 4 data2 points (3 float4 each)

// ws layout: partial mins ws[c2][bt][p], c2 in [0,64), p in [0,4096) -> 8 MB.
// Plain coalesced stores (no atomics, no init). Mean accumulated into d_out
// via one atomicAdd per reduce block; d_out zeroed by hd_partial block 0.

// Kernel 1: one block per (bt, set1-chunk c1, data2-chunk c2).
// grid = 2048 blocks = 8 blocks/CU = 8 waves/SIMD (was 4) -> latency hiding
// for the block-uniform s_load stream and the prologue set1 loads.
// data2 chunk read via BLOCK-UNIFORM addresses (no threadIdx in the address
// math) -> backend scalarizes to s_load; coords live in SGPRs, feeding the
// dot-product fmas directly (1 SGPR operand per VALU instr — legal).
// Inner math: s = q2 - 2*dot = d^2 - q1 via 3 fma (set1 pre-scaled by -2);
// q1 added once in the epilogue. 4.25 VALU instr/pair, zero LDS traffic.
__global__ __launch_bounds__(kBLK, 8) void hd_partial(
    const float* __restrict__ d1, const float* __restrict__ d2,
    float* __restrict__ ws, float* __restrict__ out)
{
    const int blk = blockIdx.x;
    const int c2  = blk % kS2C;
    const int t2  = blk / kS2C;
    const int c1  = t2 % kS1C;
    const int bt  = t2 / kS1C;

    const int tid = threadIdx.x;

    // Zero the 2 output accumulators (poisoned 0xAA by the harness each iter).
    // Stream order guarantees this retires before hd_reduce's atomicAdds.
    if (blk == 0 && tid < kB) out[tid] = 0.0f;

    // Per-thread set1 points (registers), pre-scaled by -2 for the fma form.
    const int p0 = c1 * kSP1 + tid;
    const float* __restrict__ base1 = d1 + (size_t)bt * kN * 3;
    float nx[kR], ny[kR], nz[kR], q1[kR], m[kR];
#pragma unroll
    for (int k = 0; k < kR; ++k) {
        const int p = p0 + k * kBLK;
        const float x = base1[p * 3 + 0];
        const float y = base1[p * 3 + 1];
        const float z = base1[p * 3 + 2];
        nx[k] = -2.0f * x; ny[k] = -2.0f * y; nz[k] = -2.0f * z;
        q1[k] = fmaf(x, x, fmaf(y, y, z * z));
        m[k]  = 3.402823466e38f;
    }

    // data2 chunk: 64 pts * 3 floats = 48 float4, all block-uniform, 16B
    // aligned (bt*12288 and c2*192 floats are multiples of 4).
    const float4* __restrict__ g2 =
        (const float4*)(d2 + (size_t)bt * kN * 3 + (size_t)c2 * kSP2 * 3);

#pragma unroll 4
    for (int g = 0; g < kNG; ++g) {
        const float4 A  = g2[3 * g + 0];
        const float4 Bv = g2[3 * g + 1];
        const float4 Cv = g2[3 * g + 2];
        const float px[4] = {A.x, A.w, Bv.z, Cv.y};
        const float py[4] = {A.y, Bv.x, Bv.w, Cv.z};
        const float pz[4] = {A.z, Bv.y, Cv.x, Cv.w};
        float s[4][kR];
#pragma unroll
        for (int j = 0; j < 4; ++j) {
            // q2 in a VGPR (wave-uniform value; avoids 2-SGPR operand limit
            // in the dot fmas below).
            const float q2 = fmaf(px[j], px[j], fmaf(py[j], py[j], pz[j] * pz[j]));
#pragma unroll
            for (int k = 0; k < kR; ++k) {
                float t = fmaf(px[j], nx[k], q2);
                t = fmaf(py[j], ny[k], t);
                s[j][k] = fmaf(pz[j], nz[k], t);
            }
        }
        // v_min3 formation: 2 three-input mins per k per group.
#pragma unroll
        for (int k = 0; k < kR; ++k) {
            m[k] = fminf(m[k], fminf(s[0][k], s[1][k]));
            m[k] = fminf(m[k], fminf(s[2][k], s[3][k]));
        }
    }

    // Coalesced partial-min store (d^2, clamped >= 0 so sqrt is safe).
    float* __restrict__ wrow = ws + ((size_t)c2 * kBT + bt) * kN;
#pragma unroll
    for (int k = 0; k < kR; ++k)
        wrow[p0 + k * kBLK] = fmaxf(m[k] + q1[k], 0.0f);
}

// Kernel 2: 128 blocks (16 per bt). Each block owns 64 float4 columns of one
// bt row; tid&63 picks the column, tid>>6 picks a 16-chunk span. 4-way LDS
// combine -> sqrt -> wave-sum -> one atomicAdd per block.
__global__ __launch_bounds__(256) void hd_reduce(
    const float4* __restrict__ ws4, float* __restrict__ out)
{
    const int bt  = blockIdx.x >> 4;      // 0..7
    const int seg = blockIdx.x & 15;      // 0..15 -> 64 float4 columns each
    const int tid = threadIdx.x;
    const int f4i = seg * 64 + (tid & 63);     // float4 index within row
    const int c0  = (tid >> 6) * (kS2C / 4);   // 16 chunks per part

    float4 m4 = make_float4(3.402823466e38f, 3.402823466e38f,
                            3.402823466e38f, 3.402823466e38f);
#pragma unroll 4
    for (int i = 0; i < kS2C / 4; ++i) {
        const float4 v = ws4[((size_t)(c0 + i) * kBT + bt) * (kN / 4) + f4i];
        m4.x = fminf(m4.x, v.x);
        m4.y = fminf(m4.y, v.y);
        m4.z = fminf(m4.z, v.z);
        m4.w = fminf(m4.w, v.w);
    }

    __shared__ float4 ls[256];
    ls[tid] = m4;
    __syncthreads();

    if (tid < 64) {
        const float4 a = ls[tid];
        const float4 b = ls[tid + 64];
        const float4 c = ls[tid + 128];
        const float4 d = ls[tid + 192];
        const float mx = fminf(fminf(a.x, b.x), fminf(c.x, d.x));
        const float my = fminf(fminf(a.y, b.y), fminf(c.y, d.y));
        const float mz = fminf(fminf(a.z, b.z), fminf(c.z, d.z));
        const float mw = fminf(fminf(a.w, b.w), fminf(c.w, d.w));
        float sum = sqrtf(mx) + sqrtf(my) + sqrtf(mz) + sqrtf(mw);

        // single-wave (64-lane) reduce
#pragma unroll
        for (int off = 32; off >= 1; off >>= 1)
            sum += __shfl_down(sum, off, 64);

        if (tid == 0)
            atomicAdd(&out[bt >> 2], sum * (1.0f / (kT * kN)));
    }
}

extern "C" void kernel_launch(void* const* d_in, const int* in_sizes, int n_in,
                              void* d_out, int out_size, void* d_ws, size_t ws_size,
                              hipStream_t stream) {
    const float* d1 = (const float*)d_in[0];
    const float* d2 = (const float*)d_in[1];
    // d_in[2] is dim == 0 -> identity swapaxes; ignored.
    float* out = (float*)d_out;
    float* ws = (float*)d_ws;

    hd_partial<<<dim3(kBT * kS1C * kS2C), dim3(kBLK), 0, stream>>>(d1, d2, ws, out);
    hd_reduce<<<dim3(kBT * 16), dim3(256), 0, stream>>>((const float4*)ws, out);
}

// Round 2
// 73.049 us; speedup vs baseline: 1.1034x; 1.1034x over previous
//
#include <hip/hip_runtime.h>
#include <math.h>

// Problem constants (setup_inputs): data1/data2 = (2, 4, 4096, 3) fp32, dim = 0.
constexpr int kB    = 2;
constexpr int kT    = 4;
constexpr int kBT   = kB * kT;      // 8 (b,t) slices
constexpr int kN    = 4096;         // points per slice (both sets)
constexpr int kBLK  = 256;          // threads per block
constexpr int kR    = 4;            // set1 points per thread-slot (q2 amortization)
constexpr int kP1   = 32;           // distinct set1 points per block
constexpr int kCHK  = kN / kP1;     // 128 set1 chunks per bt slice
constexpr int kREP  = kBLK * kR / kP1;  // 32 d2-replicas (rep = tid>>3)
constexpr int kD2T  = kN / kREP;    // 128 data2 points per thread
constexpr int kNG   = kD2T / 4;     // 32 groups of 4 data2 points (3 float4 each)

// Single fused kernel: one block per (bt, 32-point set1 chunk); the block
// sweeps ALL 4096 data2 points (split 32 ways across thread-replicas), so no
// partial-min matrix exists -> no 8 MB ws traffic, no hd_reduce HBM sweep.
//
// Thread layout: pset = tid&7 owns set1 points chunkBase + pset*4 + k
// (k<4, 32x replicated); rep = tid>>3 owns data2 slice [rep*128, rep*128+128).
// Wave w covers reps 8w..8w+7 = data2 [1024w, 1024w+1024) -> the 32-way min
// combine is 3 shfl_xor rounds (8,16,32) + a 4-wave LDS combine (512 B).
//
// Inner math identical to the proven hd_partial loop: s = q2 - 2*dot
// (set1 pre-scaled by -2), q1 added once at the end; 4.25 VALU instr/pair.
__global__ __launch_bounds__(kBLK, 4) void hd_main(
    const float* __restrict__ d1, const float* __restrict__ d2,
    float* __restrict__ ws)
{
    const int blk  = blockIdx.x;
    const int bt   = blk >> 7;            // 0..7
    const int cbase = (blk & 127) * kP1;  // set1 chunk base within slice
    const int tid  = threadIdx.x;
    const int pset = tid & 7;
    const int rep  = tid >> 3;

    // Per-thread set1 points (registers), pre-scaled by -2 for the fma form.
    const float* __restrict__ base1 = d1 + (size_t)bt * kN * 3;
    float nx[kR], ny[kR], nz[kR], m[kR];
#pragma unroll
    for (int k = 0; k < kR; ++k) {
        const int p = cbase + pset * 4 + k;
        const float x = base1[p * 3 + 0];
        const float y = base1[p * 3 + 1];
        const float z = base1[p * 3 + 2];
        nx[k] = -2.0f * x; ny[k] = -2.0f * y; nz[k] = -2.0f * z;
        m[k]  = 3.402823466e38f;
    }

    // This thread's data2 slice: 128 pts * 3 floats = 96 float4, 16B aligned
    // (bt*12288 and rep*384 floats are multiples of 4). 8 lanes share each
    // address -> one 128B-useful load instr per float4 across the wave.
    const float4* __restrict__ g2 =
        (const float4*)(d2 + (size_t)bt * kN * 3 + (size_t)rep * kD2T * 3);

#pragma unroll 4
    for (int g = 0; g < kNG; ++g) {
        const float4 A  = g2[3 * g + 0];
        const float4 Bv = g2[3 * g + 1];
        const float4 Cv = g2[3 * g + 2];
        const float px[4] = {A.x, A.w, Bv.z, Cv.y};
        const float py[4] = {A.y, Bv.x, Bv.w, Cv.z};
        const float pz[4] = {A.z, Bv.y, Cv.x, Cv.w};
        float s[4][kR];
#pragma unroll
        for (int j = 0; j < 4; ++j) {
            const float q2 = fmaf(px[j], px[j], fmaf(py[j], py[j], pz[j] * pz[j]));
#pragma unroll
            for (int k = 0; k < kR; ++k) {
                float t = fmaf(px[j], nx[k], q2);
                t = fmaf(py[j], ny[k], t);
                s[j][k] = fmaf(pz[j], nz[k], t);
            }
        }
        // v_min3 formation: 2 three-input mins per k per group.
#pragma unroll
        for (int k = 0; k < kR; ++k) {
            m[k] = fminf(m[k], fminf(s[0][k], s[1][k]));
            m[k] = fminf(m[k], fminf(s[2][k], s[3][k]));
        }
    }

    // Combine the 32 replicas. Within a wave the 8 replicas of a pset differ
    // in lane bits 3..5 -> butterfly over 8,16,32.
#pragma unroll
    for (int off = 8; off <= 32; off <<= 1) {
#pragma unroll
        for (int k = 0; k < kR; ++k)
            m[k] = fminf(m[k], __shfl_xor(m[k], off, 64));
    }

    __shared__ float ls[4][kP1];          // [wave][point-in-chunk]
    const int lane = tid & 63;
    const int wav  = tid >> 6;
    if (lane < 8) {
#pragma unroll
        for (int k = 0; k < kR; ++k) ls[wav][lane * 4 + k] = m[k];
    }
    __syncthreads();

    // First 32 threads: cross-wave min for set1 point (cbase + tid), add q1,
    // sqrt, then sum the 32 distances and emit one partial per block.
    float sum = 0.0f;
    if (tid < kP1) {
        const float v = fminf(fminf(ls[0][tid], ls[1][tid]),
                              fminf(ls[2][tid], ls[3][tid]));
        const int p = cbase + tid;
        const float x = base1[p * 3 + 0];
        const float y = base1[p * 3 + 1];
        const float z = base1[p * 3 + 2];
        const float q1 = fmaf(x, x, fmaf(y, y, z * z));
        sum = sqrtf(fmaxf(v + q1, 0.0f));
#pragma unroll
        for (int off = 16; off >= 1; off >>= 1)
            sum += __shfl_down(sum, off, 64);
        if (tid == 0) ws[blk] = sum;      // plain store, no atomics
    }
}

// Finisher: one block, 1024 threads; ws[0..511] -> out[0], ws[512..1023] ->
// out[1]. Plain stores -> no zero-init of out needed (poison overwritten).
__global__ __launch_bounds__(1024) void hd_final(
    const float* __restrict__ ws, float* __restrict__ out)
{
    const int tid = threadIdx.x;
    float sum = ws[tid];
#pragma unroll
    for (int off = 32; off >= 1; off >>= 1)
        sum += __shfl_down(sum, off, 64);

    __shared__ float ls[16];
    if ((tid & 63) == 0) ls[tid >> 6] = sum;
    __syncthreads();
    if (tid == 0) {
        float a = 0.0f, b = 0.0f;
#pragma unroll
        for (int w = 0; w < 8; ++w) { a += ls[w]; b += ls[w + 8]; }
        const float scale = 1.0f / (kT * kN);
        out[0] = a * scale;
        out[1] = b * scale;
    }
}

extern "C" void kernel_launch(void* const* d_in, const int* in_sizes, int n_in,
                              void* d_out, int out_size, void* d_ws, size_t ws_size,
                              hipStream_t stream) {
    const float* d1 = (const float*)d_in[0];
    const float* d2 = (const float*)d_in[1];
    // d_in[2] is dim == 0 -> identity swapaxes; ignored.
    float* out = (float*)d_out;
    float* ws = (float*)d_ws;

    hd_main<<<dim3(kBT * kCHK), dim3(kBLK), 0, stream>>>(d1, d2, ws);
    hd_final<<<dim3(1), dim3(1024), 0, stream>>>(ws, out);
}